// Round 4
// baseline (7994.247 us; speedup 1.0000x reference)
//
#include <hip/hip_runtime.h>
#include <hip/hip_bf16.h>
#include <math.h>

#define Tt 64
#define Bb 32
#define Hh 512
#define EMBe 256
#define Ee 128
#define Ss 35
#define Vv 50257
#define Kk 896
#define TCc 32

typedef __bf16 bf16_t;
typedef __bf16 bf16x8 __attribute__((ext_vector_type(8)));
typedef float f32x4 __attribute__((ext_vector_type(4)));

__device__ __forceinline__ float sigf(float x){ return 1.f/(1.f + expf(-x)); }

#define DOT4(acc, W_, H_) acc += (W_).x*(H_).x + (W_).y*(H_).y + (W_).z*(H_).z + (W_).w*(H_).w

// ---- K0a: condition embeddings -> enc rows 0..2  (enc layout [s][b][e])
__global__ void k_cond_emb(const int* __restrict__ cond, const float* __restrict__ t0,
                           const float* __restrict__ t1, const float* __restrict__ t2,
                           float* __restrict__ enc){
  int g = blockIdx.x*blockDim.x + threadIdx.x;
  if (g >= 3*Bb*Ee) return;
  int i = g/(Bb*Ee); int b = (g/Ee)%Bb; int e = g%Ee;
  const float* tbl = (i==0)? t0 : (i==1)? t1 : t2;
  int ci = cond[i*Bb + b];
  enc[(size_t)i*Bb*Ee + b*Ee + e] = tbl[(size_t)ci*Ee + e];
}

// ---- K0b: cxw[t,b,g] = cseq_emb[cond_seq[t,b]] . cgru_Wih[g] + bih[g]
__global__ void k_cxw(const int* __restrict__ cond_seq, const float* __restrict__ cemb,
                      const float* __restrict__ Wih, const float* __restrict__ bih,
                      float* __restrict__ cxw){
  __shared__ float es[Ee];
  int row = blockIdx.x; int tid = threadIdx.x; // 128 threads
  int idx = cond_seq[row];
  es[tid] = cemb[(size_t)idx*Ee + tid];
  __syncthreads();
  const float4* hp = (const float4*)es;
  for (int q = 0; q < 3; ++q){
    int g = q*Ee + tid;
    const float4* wr = (const float4*)(Wih + (size_t)g*Ee);
    float acc = bih[g];
    #pragma unroll 8
    for (int k = 0; k < Ee/4; ++k){ float4 w4 = wr[k]; float4 h4 = hp[k]; DOT4(acc, w4, h4); }
    cxw[(size_t)row*(3*Ee) + g] = acc;
  }
}

// ---- K0c: xw[t,b,g] = embedding[input[t,b]] . gru_Wih[g] + bih[g]
__global__ void k_xw(const int* __restrict__ input_data, const float* __restrict__ emb,
                     const float* __restrict__ Wih, const float* __restrict__ bih,
                     float* __restrict__ xw){
  __shared__ float es[EMBe];
  int row = blockIdx.x; int tid = threadIdx.x; // 256 threads
  int idx = input_data[row];
  es[tid] = emb[(size_t)idx*EMBe + tid];
  __syncthreads();
  const float4* hp = (const float4*)es;
  for (int q = 0; q < 6; ++q){
    int g = q*256 + tid;
    const float4* wr = (const float4*)(Wih + (size_t)g*EMBe);
    float acc = bih[g];
    #pragma unroll 8
    for (int k = 0; k < EMBe/4; ++k){ float4 w4 = wr[k]; float4 h4 = hp[k]; DOT4(acc, w4, h4); }
    xw[(size_t)row*(3*Hh) + g] = acc;
  }
}

// ---- K1: cseq GRU scan (one block per batch), writes enc rows 3..34
__global__ void k_cseq_scan(const float* __restrict__ cxw, const float* __restrict__ Whh,
                            const float* __restrict__ bhh, float* __restrict__ enc){
  __shared__ float hs[Ee];
  int b = blockIdx.x; int j = threadIdx.x; // 128 threads
  hs[j] = 0.f; __syncthreads();
  const float4* W0 = (const float4*)(Whh + (size_t)j*Ee);
  const float4* W1 = (const float4*)(Whh + (size_t)(Ee + j)*Ee);
  const float4* W2 = (const float4*)(Whh + (size_t)(2*Ee + j)*Ee);
  float b0 = bhh[j], b1 = bhh[Ee+j], b2 = bhh[2*Ee+j];
  for (int t = 0; t < TCc; ++t){
    const float* xp = cxw + ((size_t)t*Bb + b)*(3*Ee);
    float a0=b0, a1=b1, a2=b2;
    const float4* hp = (const float4*)hs;
    #pragma unroll 8
    for (int k = 0; k < Ee/4; ++k){
      float4 h4 = hp[k];
      float4 w0 = W0[k]; DOT4(a0, w0, h4);
      float4 w1 = W1[k]; DOT4(a1, w1, h4);
      float4 w2 = W2[k]; DOT4(a2, w2, h4);
    }
    float r = sigf(xp[j] + a0);
    float z = sigf(xp[Ee + j] + a1);
    float n = tanhf(xp[2*Ee + j] + r*a2);
    float hcur = hs[j];
    float hn = (1.f - z)*n + z*hcur;
    __syncthreads();
    hs[j] = hn;
    enc[(size_t)(3+t)*Bb*Ee + b*Ee + j] = hn;
    __syncthreads();
  }
}

// ---- K2: enc_proj[b,s,h] = enc[s,b,:] . W_e[h,:]   (W_e = attn_W[:, :E])
__global__ void k_encproj(const float* __restrict__ enc, const float* __restrict__ attn_W,
                          float* __restrict__ enc_proj){
  __shared__ float es[Ee];
  int blk = blockIdx.x; int tid = threadIdx.x; // 256 threads, blk = b*35+s
  int b = blk/Ss, s = blk%Ss;
  if (tid < Ee) es[tid] = enc[(size_t)s*Bb*Ee + b*Ee + tid];
  __syncthreads();
  const float4* hp = (const float4*)es;
  for (int q = 0; q < 2; ++q){
    int hh = q*256 + tid;
    const float4* wr = (const float4*)(attn_W + (size_t)hh*(Ee+Hh));
    float acc = 0.f;
    #pragma unroll 8
    for (int k = 0; k < Ee/4; ++k){ float4 w4 = wr[k]; float4 h4 = hp[k]; DOT4(acc, w4, h4); }
    enc_proj[(size_t)blk*Hh + hh] = acc;
  }
}

// ---- K3: main GRU scan. 32 blocks (batch) x 512 threads; h_all[t] = h BEFORE step t.
__global__ void k_scan(const float* __restrict__ xw, const float* __restrict__ Whh,
                       const float* __restrict__ bhh, float* __restrict__ h_all){
  __shared__ float hs[Hh];
  int b = blockIdx.x, j = threadIdx.x; // 512 threads
  hs[j] = 0.f;
  h_all[(size_t)b*Hh + j] = 0.f;  // h_all[0]
  __syncthreads();
  const float4* W0 = (const float4*)(Whh + (size_t)j*Hh);
  const float4* W1 = (const float4*)(Whh + (size_t)(Hh + j)*Hh);
  const float4* W2 = (const float4*)(Whh + (size_t)(2*Hh + j)*Hh);
  float b0 = bhh[j], b1 = bhh[Hh+j], b2 = bhh[2*Hh+j];
  for (int t = 0; t < Tt; ++t){
    const float* xp = xw + ((size_t)t*Bb + b)*(3*Hh);
    float a0=b0, a1=b1, a2=b2;
    const float4* hp = (const float4*)hs;
    #pragma unroll 4
    for (int k = 0; k < Hh/4; ++k){
      float4 h4 = hp[k];
      float4 w0 = W0[k]; DOT4(a0, w0, h4);
      float4 w1 = W1[k]; DOT4(a1, w1, h4);
      float4 w2 = W2[k]; DOT4(a2, w2, h4);
    }
    float r = sigf(xp[j] + a0);
    float z = sigf(xp[Hh + j] + a1);
    float n = tanhf(xp[2*Hh + j] + r*a2);
    float hcur = hs[j];
    float hn = (1.f - z)*n + z*hcur;
    __syncthreads();
    hs[j] = hn;
    h_all[((size_t)(t+1)*Bb + b)*Hh + j] = hn;
    __syncthreads();
  }
}

// ---- K4: hw_attn[row,h] = h_all[row,:] . W_h[h,:] + attn_b[h]  (W_h = attn_W[:, E:])
__global__ void k_hwattn(const float* __restrict__ h_all, const float* __restrict__ attn_W,
                         const float* __restrict__ attn_b, float* __restrict__ hw_attn){
  __shared__ float hsr[Hh];
  int row = blockIdx.x, tid = threadIdx.x; // 256 threads
  hsr[tid]       = h_all[(size_t)row*Hh + tid];
  hsr[256 + tid] = h_all[(size_t)row*Hh + 256 + tid];
  __syncthreads();
  const float4* hp = (const float4*)hsr;
  for (int q = 0; q < 2; ++q){
    int hh = q*256 + tid;
    const float4* wr = (const float4*)(attn_W + (size_t)hh*(Ee+Hh) + Ee);
    float acc = attn_b[hh];
    #pragma unroll 4
    for (int k = 0; k < Hh/4; ++k){ float4 w4 = wr[k]; float4 h4 = hp[k]; DOT4(acc, w4, h4); }
    hw_attn[(size_t)row*Hh + hh] = acc;
  }
}

// ---- K5: score + softmax + context. One wave per (t,b) row.
__global__ void k_score(const float* __restrict__ hw_attn, const float* __restrict__ enc_proj,
                        const float* __restrict__ enc, const float* __restrict__ vW,
                        float* __restrict__ w_out, float* __restrict__ c_all){
  __shared__ float hws[Hh];
  __shared__ float sc[Ss];
  __shared__ float wsm[Ss];
  int row = blockIdx.x, lane = threadIdx.x; // 64 threads
  int b = row & (Bb-1);
  for (int k = lane; k < Hh; k += 64) hws[k] = hw_attn[(size_t)row*Hh + k];
  __syncthreads();
  for (int s = 0; s < Ss; ++s){
    const float* ep = enc_proj + ((size_t)b*Ss + s)*Hh;
    float acc = 0.f;
    for (int k = lane; k < Hh; k += 64) acc += tanhf(ep[k] + hws[k]) * vW[k];
    #pragma unroll
    for (int off = 32; off > 0; off >>= 1) acc += __shfl_xor(acc, off);
    if (lane == 0) sc[s] = acc;
  }
  __syncthreads();
  float val = (lane < Ss) ? sc[lane] : -3.0e38f;
  float mx = val;
  #pragma unroll
  for (int off = 32; off > 0; off >>= 1) mx = fmaxf(mx, __shfl_xor(mx, off));
  float e = (lane < Ss) ? expf(val - mx) : 0.f;
  float sm = e;
  #pragma unroll
  for (int off = 32; off > 0; off >>= 1) sm += __shfl_xor(sm, off);
  float w = e / sm;
  if (lane < Ss){ w_out[(size_t)row*Ss + lane] = w; wsm[lane] = w; }
  __syncthreads();
  for (int q = 0; q < 2; ++q){
    int ee = q*64 + lane;
    float acc = 0.f;
    #pragma unroll
    for (int s = 0; s < Ss; ++s) acc += wsm[s]*enc[(size_t)s*Bb*Ee + b*Ee + ee];
    c_all[(size_t)row*Ee + ee] = acc;
  }
}

// ---- K6: build A = [c | x_emb | h] as bf16, row-major [2048][896]
__global__ void k_abuild(const int* __restrict__ input_data, const float* __restrict__ c_all,
                         const float* __restrict__ embedding, const float* __restrict__ h_all,
                         bf16_t* __restrict__ A){
  int row = blockIdx.x, tid = threadIdx.x; // 256 threads
  int xidx = input_data[row];
  bf16_t* Ar = A + (size_t)row*Kk;
  for (int col = tid; col < Kk; col += 256){
    float v;
    if (col < Ee) v = c_all[(size_t)row*Ee + col];
    else if (col < Ee + EMBe) v = embedding[(size_t)xidx*EMBe + (col - Ee)];
    else v = h_all[(size_t)row*Hh + (col - Ee - EMBe)];
    Ar[col] = (bf16_t)v;
  }
}

// ---- K7: dense GEMM: out[m, v] = A[m,:] . Wd[v,:] + bias[v]
//      block owns 64 W-rows resident in LDS (bf16), loops over 16 M-tiles of 128.
#define WS_STRIDE 920
#define AS_STRIDE 72
#define GEMM_LDS ((64*WS_STRIDE + 128*AS_STRIDE)*2)

__global__ __launch_bounds__(256) void k_gemm(const bf16_t* __restrict__ A,
                                              const float* __restrict__ Wd,
                                              const float* __restrict__ bias,
                                              float* __restrict__ out){
  extern __shared__ char smem[];
  bf16_t* Ws = (bf16_t*)smem;
  bf16_t* As = (bf16_t*)(smem + (size_t)64*WS_STRIDE*2);
  int tid = threadIdx.x;
  int n0 = blockIdx.x*64;
  // stage W rows (fp32 -> bf16), zero-fill out-of-range rows
  for (int r = 0; r < 64; ++r){
    int v = n0 + r;
    const float* src = Wd + (size_t)v*Kk;
    for (int c = tid; c < Kk; c += 256){
      float x = (v < Vv) ? src[c] : 0.f;
      Ws[r*WS_STRIDE + c] = (bf16_t)x;
    }
  }
  __syncthreads();
  int wave = tid >> 6, lane = tid & 63;
  int l15 = lane & 15, l4 = lane >> 4;
  int arow = tid >> 1, ahf = tid & 1;
  for (int mt = 0; mt < 16; ++mt){
    int m0 = mt*128;
    f32x4 acc[2][4];
    #pragma unroll
    for (int i2 = 0; i2 < 2; ++i2)
      #pragma unroll
      for (int j2 = 0; j2 < 4; ++j2) acc[i2][j2] = (f32x4){0.f,0.f,0.f,0.f};
    for (int kk = 0; kk < Kk/64; ++kk){
      __syncthreads();
      { // stage A tile [128 x 64]: each thread copies 32 bf16 (4 x int4)
        const int4* src = (const int4*)(A + (size_t)(m0 + arow)*Kk + kk*64 + ahf*32);
        int4* dst = (int4*)(As + arow*AS_STRIDE + ahf*32);
        int4 v0 = src[0], v1 = src[1], v2 = src[2], v3 = src[3];
        dst[0]=v0; dst[1]=v1; dst[2]=v2; dst[3]=v3;
      }
      __syncthreads();
      #pragma unroll
      for (int k32 = 0; k32 < 2; ++k32){
        bf16x8 a0 = *(const bf16x8*)(As + (wave*32 +      l15)*AS_STRIDE + k32*32 + l4*8);
        bf16x8 a1 = *(const bf16x8*)(As + (wave*32 + 16 + l15)*AS_STRIDE + k32*32 + l4*8);
        int kbase = kk*64 + k32*32 + l4*8;
        #pragma unroll
        for (int nf = 0; nf < 4; ++nf){
          bf16x8 bfr = *(const bf16x8*)(Ws + (nf*16 + l15)*WS_STRIDE + kbase);
          acc[0][nf] = __builtin_amdgcn_mfma_f32_16x16x32_bf16(a0, bfr, acc[0][nf], 0, 0, 0);
          acc[1][nf] = __builtin_amdgcn_mfma_f32_16x16x32_bf16(a1, bfr, acc[1][nf], 0, 0, 0);
        }
      }
    }
    // epilogue: D[row][col]: row(M) = (l>>4)*4 + reg, col(N) = l&15  (m89-verified)
    #pragma unroll
    for (int mf = 0; mf < 2; ++mf){
      #pragma unroll
      for (int nf = 0; nf < 4; ++nf){
        int v = n0 + nf*16 + l15;
        if (v < Vv){
          float bv = bias[v];
          int m = m0 + wave*32 + mf*16 + l4*4;
          #pragma unroll
          for (int i = 0; i < 4; ++i){
            out[(size_t)(m + i)*Vv + v] = acc[mf][nf][i] + bv;
          }
        }
      }
    }
  }
}

// ---- K8: per-row online logsumexp
__global__ void k_lse(const float* __restrict__ pred, float* __restrict__ lse){
  __shared__ float ms[256], ssum[256];
  int row = blockIdx.x, tid = threadIdx.x;
  const float* p = pred + (size_t)row*Vv;
  float m = -3.0e38f, s = 0.f;
  for (int v = tid; v < Vv; v += 256){
    float x = p[v];
    if (x > m){ s = s*expf(m - x) + 1.f; m = x; }
    else s += expf(x - m);
  }
  ms[tid] = m; ssum[tid] = s;
  __syncthreads();
  for (int off = 128; off > 0; off >>= 1){
    if (tid < off){
      float m2 = ms[tid+off], s2 = ssum[tid+off];
      float m1 = ms[tid],     s1 = ssum[tid];
      if (m2 > m1){ s1 = s1*expf(m1 - m2) + s2; m1 = m2; }
      else s1 += s2*expf(m2 - m1);
      ms[tid] = m1; ssum[tid] = s1;
    }
    __syncthreads();
  }
  if (tid == 0) lse[row] = ms[0] + logf(ssum[0]);
}

// ---- K9: pred -= lse[row]
__global__ void k_sub(float* __restrict__ pred, const float* __restrict__ lse){
  int row = blockIdx.x, tid = threadIdx.x;
  float l = lse[row];
  float* p = pred + (size_t)row*Vv;
  for (int v = tid; v < Vv; v += 256) p[v] -= l;
}

// ---- K10: copy hT
__global__ void k_hT(const float* __restrict__ h_all, float* __restrict__ hT){
  int g = blockIdx.x*256 + threadIdx.x;
  if (g < Bb*Hh) hT[g] = h_all[(size_t)Tt*Bb*Hh + g];
}

extern "C" void kernel_launch(void* const* d_in, const int* in_sizes, int n_in,
                              void* d_out, int out_size, void* d_ws, size_t ws_size,
                              hipStream_t stream){
  const int*   input_data = (const int*)d_in[0];
  const int*   condition  = (const int*)d_in[1];
  const int*   cond_seq   = (const int*)d_in[2];
  const float* emb_c0     = (const float*)d_in[3];
  const float* emb_c1     = (const float*)d_in[4];
  const float* emb_c2     = (const float*)d_in[5];
  const float* cseq_emb   = (const float*)d_in[6];
  const float* embedding  = (const float*)d_in[7];
  const float* attn_W     = (const float*)d_in[8];
  const float* attn_b     = (const float*)d_in[9];
  const float* v_W        = (const float*)d_in[10];
  const float* gru_Wih    = (const float*)d_in[11];
  const float* gru_Whh    = (const float*)d_in[12];
  const float* gru_bih    = (const float*)d_in[13];
  const float* gru_bhh    = (const float*)d_in[14];
  const float* cgru_Wih   = (const float*)d_in[15];
  const float* cgru_Whh   = (const float*)d_in[16];
  const float* cgru_bih   = (const float*)d_in[17];
  const float* cgru_bhh   = (const float*)d_in[18];
  const float* dense_W    = (const float*)d_in[19];
  const float* dense_b    = (const float*)d_in[20];

  float* out    = (float*)d_out;
  float* pred   = out;                              // [2048][V]
  float* hT_out = out + (size_t)Tt*Bb*Vv;           // [32][512]
  float* w_out  = hT_out + (size_t)Bb*Hh;           // [2048][35]

  float* ws       = (float*)d_ws;
  float* h_all    = ws;                                   // 65*32*512
  float* xw       = h_all + (size_t)(Tt+1)*Bb*Hh;         // 64*32*1536
  float* cxw      = xw + (size_t)Tt*Bb*3*Hh;              // 32*32*384
  float* enc      = cxw + (size_t)TCc*Bb*3*Ee;            // 35*32*128
  float* enc_proj = enc + (size_t)Ss*Bb*Ee;               // 32*35*512
  float* hw_attn  = enc_proj + (size_t)Bb*Ss*Hh;          // 64*32*512
  float* c_all    = hw_attn + (size_t)Tt*Bb*Hh;           // 64*32*128
  float* lse      = c_all + (size_t)Tt*Bb*Ee;             // 2048
  bf16_t* Abf     = (bf16_t*)(lse + Tt*Bb);               // 2048*896 bf16

  k_cond_emb<<<48, 256, 0, stream>>>(condition, emb_c0, emb_c1, emb_c2, enc);
  k_cxw<<<TCc*Bb, 128, 0, stream>>>(cond_seq, cseq_emb, cgru_Wih, cgru_bih, cxw);
  k_xw<<<Tt*Bb, 256, 0, stream>>>(input_data, embedding, gru_Wih, gru_bih, xw);
  k_cseq_scan<<<Bb, Ee, 0, stream>>>(cxw, cgru_Whh, cgru_bhh, enc);
  k_encproj<<<Bb*Ss, 256, 0, stream>>>(enc, attn_W, enc_proj);
  k_scan<<<Bb, Hh, 0, stream>>>(xw, gru_Whh, gru_bhh, h_all);
  k_hwattn<<<Tt*Bb, 256, 0, stream>>>(h_all, attn_W, attn_b, hw_attn);
  k_score<<<Tt*Bb, 64, 0, stream>>>(hw_attn, enc_proj, enc, v_W, w_out, c_all);
  k_abuild<<<Tt*Bb, 256, 0, stream>>>(input_data, c_all, embedding, h_all, Abf);

  (void)hipFuncSetAttribute((const void*)k_gemm, hipFuncAttributeMaxDynamicSharedMemorySize, GEMM_LDS);
  k_gemm<<<(Vv + 63)/64, 256, GEMM_LDS, stream>>>(Abf, dense_W, dense_b, pred);

  k_lse<<<Tt*Bb, 256, 0, stream>>>(pred, lse);
  k_sub<<<Tt*Bb, 256, 0, stream>>>(pred, lse);
  k_hT<<<64, 256, 0, stream>>>(h_all, hT_out);
}

// Round 5
// 3246.033 us; speedup vs baseline: 2.4628x; 2.4628x over previous
//
#include <hip/hip_runtime.h>
#include <hip/hip_bf16.h>
#include <hip/hip_cooperative_groups.h>
#include <math.h>

namespace cg = cooperative_groups;

#define Tt 64
#define Bb 32
#define Hh 512
#define EMBe 256
#define Ee 128
#define Ss 35
#define Vv 50257
#define Kk 896
#define TCc 32

typedef __bf16 bf16_t;
typedef __bf16 bf16x8 __attribute__((ext_vector_type(8)));
typedef float f32x4 __attribute__((ext_vector_type(4)));

__device__ __forceinline__ float sigf(float x){ return 1.f/(1.f + expf(-x)); }

#define DOT4(acc, W_, H_) acc += (W_).x*(H_).x + (W_).y*(H_).y + (W_).z*(H_).z + (W_).w*(H_).w

// ---- K0a: condition embeddings -> enc rows 0..2  (enc layout [s][b][e])
__global__ void k_cond_emb(const int* __restrict__ cond, const float* __restrict__ t0,
                           const float* __restrict__ t1, const float* __restrict__ t2,
                           float* __restrict__ enc){
  int g = blockIdx.x*blockDim.x + threadIdx.x;
  if (g >= 3*Bb*Ee) return;
  int i = g/(Bb*Ee); int b = (g/Ee)%Bb; int e = g%Ee;
  const float* tbl = (i==0)? t0 : (i==1)? t1 : t2;
  int ci = cond[i*Bb + b];
  enc[(size_t)i*Bb*Ee + b*Ee + e] = tbl[(size_t)ci*Ee + e];
}

// ---- K0b: cxw[t,b,g] = cseq_emb[cond_seq[t,b]] . cgru_Wih[g] + bih[g]
__global__ void k_cxw(const int* __restrict__ cond_seq, const float* __restrict__ cemb,
                      const float* __restrict__ Wih, const float* __restrict__ bih,
                      float* __restrict__ cxw){
  __shared__ float es[Ee];
  int row = blockIdx.x; int tid = threadIdx.x; // 128 threads
  int idx = cond_seq[row];
  es[tid] = cemb[(size_t)idx*Ee + tid];
  __syncthreads();
  const float4* hp = (const float4*)es;
  for (int q = 0; q < 3; ++q){
    int g = q*Ee + tid;
    const float4* wr = (const float4*)(Wih + (size_t)g*Ee);
    float acc = bih[g];
    #pragma unroll 8
    for (int k = 0; k < Ee/4; ++k){ float4 w4 = wr[k]; float4 h4 = hp[k]; DOT4(acc, w4, h4); }
    cxw[(size_t)row*(3*Ee) + g] = acc;
  }
}

// ---- K0c: xw[t,b,g] = embedding[input[t,b]] . gru_Wih[g] + bih[g]
__global__ void k_xw(const int* __restrict__ input_data, const float* __restrict__ emb,
                     const float* __restrict__ Wih, const float* __restrict__ bih,
                     float* __restrict__ xw){
  __shared__ float es[EMBe];
  int row = blockIdx.x; int tid = threadIdx.x; // 256 threads
  int idx = input_data[row];
  es[tid] = emb[(size_t)idx*EMBe + tid];
  __syncthreads();
  const float4* hp = (const float4*)es;
  for (int q = 0; q < 6; ++q){
    int g = q*256 + tid;
    const float4* wr = (const float4*)(Wih + (size_t)g*EMBe);
    float acc = bih[g];
    #pragma unroll 8
    for (int k = 0; k < EMBe/4; ++k){ float4 w4 = wr[k]; float4 h4 = hp[k]; DOT4(acc, w4, h4); }
    xw[(size_t)row*(3*Hh) + g] = acc;
  }
}

// ---- transpose cgru_Whh [384][128] -> WT [128][384]
__global__ void k_ctrans(const float* __restrict__ W, float* __restrict__ WT){
  int idx = blockIdx.x*256 + threadIdx.x;
  if (idx >= 3*Ee*Ee) return;
  int g = idx/Ee, k = idx%Ee;
  WT[(size_t)k*(3*Ee) + g] = W[idx];
}

// ---- K1: cseq GRU scan (one block per batch), coalesced via WT, writes enc rows 3..34
__global__ void k_cseq_scan(const float* __restrict__ cxw, const float* __restrict__ WT,
                            const float* __restrict__ bhh, float* __restrict__ enc){
  __shared__ float hs[Ee];
  int b = blockIdx.x; int j = threadIdx.x; // 128 threads
  hs[j] = 0.f; __syncthreads();
  float b0 = bhh[j], b1 = bhh[Ee+j], b2 = bhh[2*Ee+j];
  for (int t = 0; t < TCc; ++t){
    const float* xp = cxw + ((size_t)t*Bb + b)*(3*Ee);
    float a0=b0, a1=b1, a2=b2;
    #pragma unroll 4
    for (int k = 0; k < Ee; ++k){
      float hk = hs[k];
      const float* wr = WT + (size_t)k*(3*Ee);
      a0 += hk * wr[j];
      a1 += hk * wr[Ee + j];
      a2 += hk * wr[2*Ee + j];
    }
    float r = sigf(xp[j] + a0);
    float z = sigf(xp[Ee + j] + a1);
    float n = tanhf(xp[2*Ee + j] + r*a2);
    float hcur = hs[j];
    float hn = (1.f - z)*n + z*hcur;
    __syncthreads();
    hs[j] = hn;
    enc[(size_t)(3+t)*Bb*Ee + b*Ee + j] = hn;
    __syncthreads();
  }
}

// ---- K2: enc_proj[b,s,h] = enc[s,b,:] . W_e[h,:]   (W_e = attn_W[:, :E])
__global__ void k_encproj(const float* __restrict__ enc, const float* __restrict__ attn_W,
                          float* __restrict__ enc_proj){
  __shared__ float es[Ee];
  int blk = blockIdx.x; int tid = threadIdx.x; // 256 threads, blk = b*35+s
  int b = blk/Ss, s = blk%Ss;
  if (tid < Ee) es[tid] = enc[(size_t)s*Bb*Ee + b*Ee + tid];
  __syncthreads();
  const float4* hp = (const float4*)es;
  for (int q = 0; q < 2; ++q){
    int hh = q*256 + tid;
    const float4* wr = (const float4*)(attn_W + (size_t)hh*(Ee+Hh));
    float acc = 0.f;
    #pragma unroll 8
    for (int k = 0; k < Ee/4; ++k){ float4 w4 = wr[k]; float4 h4 = hp[k]; DOT4(acc, w4, h4); }
    enc_proj[(size_t)blk*Hh + hh] = acc;
  }
}

// ---- K3: cooperative main GRU scan.
// 16 blocks x 384 threads (6 waves). Block owns h-cols [c0, c0+32).
// Whh slice (96 rows x 512) resident in LDS as bf16 for all 64 steps.
// Per step: stage full h (bf16) to LDS, MFMA gates, fp32 combine (h carried in regs),
// write h_all fp32 + h bf16 double-buffer, grid sync.
#define SCAN_BLOCKS 16
#define SCAN_THREADS 384
#define WSL_STRIDE 520
#define HST_STRIDE 520
#define GW_STRIDE 104
#define SCAN_LDS (96*WSL_STRIDE*2 + Bb*HST_STRIDE*2 + Bb*GW_STRIDE*4)

__global__ __launch_bounds__(SCAN_THREADS) void k_scan_coop(
    const float* __restrict__ xw, const float* __restrict__ Whh,
    const float* __restrict__ bhh, float* __restrict__ h_all,
    bf16_t* __restrict__ hb0, bf16_t* __restrict__ hb1){
  extern __shared__ char smem[];
  bf16_t* Wsl = (bf16_t*)smem;
  bf16_t* hst = (bf16_t*)(smem + 96*WSL_STRIDE*2);
  float*  gw  = (float*) (smem + 96*WSL_STRIDE*2 + Bb*HST_STRIDE*2);
  const int tid = threadIdx.x;
  const int blk = blockIdx.x;
  const int c0 = blk*32;

  // load Whh slice: local row lr = g*32+i <-> global row g*512 + c0 + i
  for (int lr = 0; lr < 96; ++lr){
    int g = lr >> 5, i = lr & 31;
    const float* src = Whh + ((size_t)g*Hh + c0 + i)*Hh;
    for (int c = tid; c < Hh; c += SCAN_THREADS)
      Wsl[lr*WSL_STRIDE + c] = (bf16_t)src[c];
  }
  // init h0 (this block's columns)
  for (int idx = tid; idx < Bb*32; idx += SCAN_THREADS){
    int b = idx >> 5, i = idx & 31;
    hb0[b*Hh + c0 + i] = (bf16_t)0.f;
    h_all[(size_t)b*Hh + c0 + i] = 0.f;
  }

  // per-thread combine items (up to 3): item = tid + 384*i over [0, 1024)
  int   ib[3], icl[3], nit = 0;
  float bhr[3], bhz[3], bhn[3], hreg[3];
  for (int i = 0; i < 3; ++i){
    int item = tid + SCAN_THREADS*i;
    if (item < Bb*32){
      ib[nit] = item >> 5; icl[nit] = item & 31;
      int j = c0 + (item & 31);
      bhr[nit] = bhh[j]; bhz[nit] = bhh[Hh + j]; bhn[nit] = bhh[2*Hh + j];
      hreg[nit] = 0.f;
      ++nit;
    }
  }

  cg::grid_group grid = cg::this_grid();
  grid.sync();

  const int wid = tid >> 6, lane = tid & 63;
  const int l15 = lane & 15, l4 = lane >> 4;

  for (int t = 0; t < Tt; ++t){
    const bf16_t* hin  = (t & 1) ? hb1 : hb0;
    bf16_t*       hout = (t & 1) ? hb0 : hb1;
    // stage full h -> LDS (vectorized, coalesced)
    for (int idx = tid; idx < Bb*Hh/8; idx += SCAN_THREADS){
      int b = idx >> 6, c8 = idx & 63;
      *(bf16x8*)(hst + b*HST_STRIDE + c8*8) = *(const bf16x8*)(hin + b*Hh + c8*8);
    }
    __syncthreads();
    // MFMA: wave wid -> ntile wid (16 gate-rows), both mtiles (batches 0-15, 16-31)
    f32x4 acc0 = {0.f,0.f,0.f,0.f}, acc1 = {0.f,0.f,0.f,0.f};
    #pragma unroll
    for (int ks = 0; ks < 16; ++ks){
      bf16x8 bfr = *(const bf16x8*)(Wsl + (wid*16 + l15)*WSL_STRIDE + ks*32 + l4*8);
      bf16x8 a0  = *(const bf16x8*)(hst + l15*HST_STRIDE        + ks*32 + l4*8);
      bf16x8 a1  = *(const bf16x8*)(hst + (16 + l15)*HST_STRIDE + ks*32 + l4*8);
      acc0 = __builtin_amdgcn_mfma_f32_16x16x32_bf16(a0, bfr, acc0, 0, 0, 0);
      acc1 = __builtin_amdgcn_mfma_f32_16x16x32_bf16(a1, bfr, acc1, 0, 0, 0);
    }
    // D layout: batch = mtile*16 + l4*4 + i, gate-col = wid*16 + l15
    #pragma unroll
    for (int i = 0; i < 4; ++i){
      gw[(l4*4 + i)*GW_STRIDE + wid*16 + l15]        = acc0[i];
      gw[(16 + l4*4 + i)*GW_STRIDE + wid*16 + l15]   = acc1[i];
    }
    __syncthreads();
    // combine (fp32 recurrence carried in registers)
    for (int i = 0; i < nit; ++i){
      int b = ib[i], cl = icl[i], j = c0 + cl;
      const float* xp = xw + ((size_t)t*Bb + b)*(3*Hh);
      float gr = gw[b*GW_STRIDE + cl]      + bhr[i];
      float gz = gw[b*GW_STRIDE + 32 + cl] + bhz[i];
      float gn = gw[b*GW_STRIDE + 64 + cl] + bhn[i];
      float r = sigf(xp[j] + gr);
      float z = sigf(xp[Hh + j] + gz);
      float n = tanhf(xp[2*Hh + j] + r*gn);
      float hn = (1.f - z)*n + z*hreg[i];
      hreg[i] = hn;
      h_all[((size_t)(t+1)*Bb + b)*Hh + j] = hn;
      hout[b*Hh + j] = (bf16_t)hn;
    }
    grid.sync();
  }
}

// ---- K4: hw_attn[row,h] = h_all[row,:] . W_h[h,:] + attn_b[h]  (W_h = attn_W[:, E:])
__global__ void k_hwattn(const float* __restrict__ h_all, const float* __restrict__ attn_W,
                         const float* __restrict__ attn_b, float* __restrict__ hw_attn){
  __shared__ float hsr[Hh];
  int row = blockIdx.x, tid = threadIdx.x; // 256 threads
  hsr[tid]       = h_all[(size_t)row*Hh + tid];
  hsr[256 + tid] = h_all[(size_t)row*Hh + 256 + tid];
  __syncthreads();
  const float4* hp = (const float4*)hsr;
  for (int q = 0; q < 2; ++q){
    int hh = q*256 + tid;
    const float4* wr = (const float4*)(attn_W + (size_t)hh*(Ee+Hh) + Ee);
    float acc = attn_b[hh];
    #pragma unroll 4
    for (int k = 0; k < Hh/4; ++k){ float4 w4 = wr[k]; float4 h4 = hp[k]; DOT4(acc, w4, h4); }
    hw_attn[(size_t)row*Hh + hh] = acc;
  }
}

// ---- K5: score + softmax + context. One wave per (t,b) row.
__global__ void k_score(const float* __restrict__ hw_attn, const float* __restrict__ enc_proj,
                        const float* __restrict__ enc, const float* __restrict__ vW,
                        float* __restrict__ w_out, float* __restrict__ c_all){
  __shared__ float hws[Hh];
  __shared__ float sc[Ss];
  __shared__ float wsm[Ss];
  int row = blockIdx.x, lane = threadIdx.x; // 64 threads
  int b = row & (Bb-1);
  for (int k = lane; k < Hh; k += 64) hws[k] = hw_attn[(size_t)row*Hh + k];
  __syncthreads();
  for (int s = 0; s < Ss; ++s){
    const float* ep = enc_proj + ((size_t)b*Ss + s)*Hh;
    float acc = 0.f;
    for (int k = lane; k < Hh; k += 64) acc += tanhf(ep[k] + hws[k]) * vW[k];
    #pragma unroll
    for (int off = 32; off > 0; off >>= 1) acc += __shfl_xor(acc, off);
    if (lane == 0) sc[s] = acc;
  }
  __syncthreads();
  float val = (lane < Ss) ? sc[lane] : -3.0e38f;
  float mx = val;
  #pragma unroll
  for (int off = 32; off > 0; off >>= 1) mx = fmaxf(mx, __shfl_xor(mx, off));
  float e = (lane < Ss) ? expf(val - mx) : 0.f;
  float sm = e;
  #pragma unroll
  for (int off = 32; off > 0; off >>= 1) sm += __shfl_xor(sm, off);
  float w = e / sm;
  if (lane < Ss){ w_out[(size_t)row*Ss + lane] = w; wsm[lane] = w; }
  __syncthreads();
  for (int q = 0; q < 2; ++q){
    int ee = q*64 + lane;
    float acc = 0.f;
    #pragma unroll
    for (int s = 0; s < Ss; ++s) acc += wsm[s]*enc[(size_t)s*Bb*Ee + b*Ee + ee];
    c_all[(size_t)row*Ee + ee] = acc;
  }
}

// ---- K6: build A = [c | x_emb | h] as bf16, row-major [2048][896]
__global__ void k_abuild(const int* __restrict__ input_data, const float* __restrict__ c_all,
                         const float* __restrict__ embedding, const float* __restrict__ h_all,
                         bf16_t* __restrict__ A){
  int row = blockIdx.x, tid = threadIdx.x; // 256 threads
  int xidx = input_data[row];
  bf16_t* Ar = A + (size_t)row*Kk;
  for (int col = tid; col < Kk; col += 256){
    float v;
    if (col < Ee) v = c_all[(size_t)row*Ee + col];
    else if (col < Ee + EMBe) v = embedding[(size_t)xidx*EMBe + (col - Ee)];
    else v = h_all[(size_t)row*Hh + (col - Ee - EMBe)];
    Ar[col] = (bf16_t)v;
  }
}

// ---- K7: dense GEMM: out[m, v] = A[m,:] . Wd[v,:] + bias[v]
#define WS_STRIDE 920
#define AS_STRIDE 72
#define GEMM_LDS ((64*WS_STRIDE + 128*AS_STRIDE)*2)

__global__ __launch_bounds__(256) void k_gemm(const bf16_t* __restrict__ A,
                                              const float* __restrict__ Wd,
                                              const float* __restrict__ bias,
                                              float* __restrict__ out){
  extern __shared__ char smem[];
  bf16_t* Ws = (bf16_t*)smem;
  bf16_t* As = (bf16_t*)(smem + (size_t)64*WS_STRIDE*2);
  int tid = threadIdx.x;
  int n0 = blockIdx.x*64;
  for (int r = 0; r < 64; ++r){
    int v = n0 + r;
    const float* src = Wd + (size_t)v*Kk;
    for (int c = tid; c < Kk; c += 256){
      float x = (v < Vv) ? src[c] : 0.f;
      Ws[r*WS_STRIDE + c] = (bf16_t)x;
    }
  }
  __syncthreads();
  int wave = tid >> 6, lane = tid & 63;
  int l15 = lane & 15, l4 = lane >> 4;
  int arow = tid >> 1, ahf = tid & 1;
  for (int mt = 0; mt < 16; ++mt){
    int m0 = mt*128;
    f32x4 acc[2][4];
    #pragma unroll
    for (int i2 = 0; i2 < 2; ++i2)
      #pragma unroll
      for (int j2 = 0; j2 < 4; ++j2) acc[i2][j2] = (f32x4){0.f,0.f,0.f,0.f};
    for (int kk = 0; kk < Kk/64; ++kk){
      __syncthreads();
      { // stage A tile [128 x 64]: each thread copies 32 bf16 (4 x int4)
        const int4* src = (const int4*)(A + (size_t)(m0 + arow)*Kk + kk*64 + ahf*32);
        int4* dst = (int4*)(As + arow*AS_STRIDE + ahf*32);
        int4 v0 = src[0], v1 = src[1], v2 = src[2], v3 = src[3];
        dst[0]=v0; dst[1]=v1; dst[2]=v2; dst[3]=v3;
      }
      __syncthreads();
      #pragma unroll
      for (int k32 = 0; k32 < 2; ++k32){
        bf16x8 a0 = *(const bf16x8*)(As + (wave*32 +      l15)*AS_STRIDE + k32*32 + l4*8);
        bf16x8 a1 = *(const bf16x8*)(As + (wave*32 + 16 + l15)*AS_STRIDE + k32*32 + l4*8);
        int kbase = kk*64 + k32*32 + l4*8;
        #pragma unroll
        for (int nf = 0; nf < 4; ++nf){
          bf16x8 bfr = *(const bf16x8*)(Ws + (nf*16 + l15)*WS_STRIDE + kbase);
          acc[0][nf] = __builtin_amdgcn_mfma_f32_16x16x32_bf16(a0, bfr, acc[0][nf], 0, 0, 0);
          acc[1][nf] = __builtin_amdgcn_mfma_f32_16x16x32_bf16(a1, bfr, acc[1][nf], 0, 0, 0);
        }
      }
    }
    #pragma unroll
    for (int mf = 0; mf < 2; ++mf){
      #pragma unroll
      for (int nf = 0; nf < 4; ++nf){
        int v = n0 + nf*16 + l15;
        if (v < Vv){
          float bv = bias[v];
          int m = m0 + wave*32 + mf*16 + l4*4;
          #pragma unroll
          for (int i = 0; i < 4; ++i){
            out[(size_t)(m + i)*Vv + v] = acc[mf][nf][i] + bv;
          }
        }
      }
    }
  }
}

// ---- K8: per-row online logsumexp
__global__ void k_lse(const float* __restrict__ pred, float* __restrict__ lse){
  __shared__ float ms[256], ssum[256];
  int row = blockIdx.x, tid = threadIdx.x;
  const float* p = pred + (size_t)row*Vv;
  float m = -3.0e38f, s = 0.f;
  for (int v = tid; v < Vv; v += 256){
    float x = p[v];
    if (x > m){ s = s*expf(m - x) + 1.f; m = x; }
    else s += expf(x - m);
  }
  ms[tid] = m; ssum[tid] = s;
  __syncthreads();
  for (int off = 128; off > 0; off >>= 1){
    if (tid < off){
      float m2 = ms[tid+off], s2 = ssum[tid+off];
      float m1 = ms[tid],     s1 = ssum[tid];
      if (m2 > m1){ s1 = s1*expf(m1 - m2) + s2; m1 = m2; }
      else s1 += s2*expf(m2 - m1);
      ms[tid] = m1; ssum[tid] = s1;
    }
    __syncthreads();
  }
  if (tid == 0) lse[row] = ms[0] + logf(ssum[0]);
}

// ---- K9: pred -= lse[row]
__global__ void k_sub(float* __restrict__ pred, const float* __restrict__ lse){
  int row = blockIdx.x, tid = threadIdx.x;
  float l = lse[row];
  float* p = pred + (size_t)row*Vv;
  for (int v = tid; v < Vv; v += 256) p[v] -= l;
}

// ---- K10: copy hT
__global__ void k_hT(const float* __restrict__ h_all, float* __restrict__ hT){
  int g = blockIdx.x*256 + threadIdx.x;
  if (g < Bb*Hh) hT[g] = h_all[(size_t)Tt*Bb*Hh + g];
}

extern "C" void kernel_launch(void* const* d_in, const int* in_sizes, int n_in,
                              void* d_out, int out_size, void* d_ws, size_t ws_size,
                              hipStream_t stream){
  const int*   input_data = (const int*)d_in[0];
  const int*   condition  = (const int*)d_in[1];
  const int*   cond_seq   = (const int*)d_in[2];
  const float* emb_c0     = (const float*)d_in[3];
  const float* emb_c1     = (const float*)d_in[4];
  const float* emb_c2     = (const float*)d_in[5];
  const float* cseq_emb   = (const float*)d_in[6];
  const float* embedding  = (const float*)d_in[7];
  const float* attn_W     = (const float*)d_in[8];
  const float* attn_b     = (const float*)d_in[9];
  const float* v_W        = (const float*)d_in[10];
  const float* gru_Wih    = (const float*)d_in[11];
  const float* gru_Whh    = (const float*)d_in[12];
  const float* gru_bih    = (const float*)d_in[13];
  const float* gru_bhh    = (const float*)d_in[14];
  const float* cgru_Wih   = (const float*)d_in[15];
  const float* cgru_Whh   = (const float*)d_in[16];
  const float* cgru_bih   = (const float*)d_in[17];
  const float* cgru_bhh   = (const float*)d_in[18];
  const float* dense_W    = (const float*)d_in[19];
  const float* dense_b    = (const float*)d_in[20];

  float* out    = (float*)d_out;
  float* pred   = out;                              // [2048][V]
  float* hT_out = out + (size_t)Tt*Bb*Vv;           // [32][512]
  float* w_out  = hT_out + (size_t)Bb*Hh;           // [2048][35]

  float* ws       = (float*)d_ws;
  float* h_all    = ws;                                   // 65*32*512
  float* xw       = h_all + (size_t)(Tt+1)*Bb*Hh;         // 64*32*1536
  float* cxw      = xw + (size_t)Tt*Bb*3*Hh;              // 32*32*384
  float* enc      = cxw + (size_t)TCc*Bb*3*Ee;            // 35*32*128
  float* enc_proj = enc + (size_t)Ss*Bb*Ee;               // 32*35*512
  float* hw_attn  = enc_proj + (size_t)Bb*Ss*Hh;          // 64*32*512
  float* c_all    = hw_attn + (size_t)Tt*Bb*Hh;           // 64*32*128
  float* lse      = c_all + (size_t)Tt*Bb*Ee;             // 2048
  bf16_t* Abf     = (bf16_t*)(lse + Tt*Bb);               // 2048*896 bf16
  float* after_A  = (float*)(Abf + (size_t)Tt*Bb*Kk);
  bf16_t* hb0     = (bf16_t*)after_A;                     // 32*512 bf16
  bf16_t* hb1     = hb0 + (size_t)Bb*Hh;                  // 32*512 bf16
  float* WTc      = (float*)(hb1 + (size_t)Bb*Hh);        // 128*384 fp32

  k_cond_emb<<<48, 256, 0, stream>>>(condition, emb_c0, emb_c1, emb_c2, enc);
  k_cxw<<<TCc*Bb, 128, 0, stream>>>(cond_seq, cseq_emb, cgru_Wih, cgru_bih, cxw);
  k_xw<<<Tt*Bb, 256, 0, stream>>>(input_data, embedding, gru_Wih, gru_bih, xw);
  k_ctrans<<<(3*Ee*Ee + 255)/256, 256, 0, stream>>>(cgru_Whh, WTc);
  k_cseq_scan<<<Bb, Ee, 0, stream>>>(cxw, WTc, cgru_bhh, enc);
  k_encproj<<<Bb*Ss, 256, 0, stream>>>(enc, attn_W, enc_proj);

  (void)hipFuncSetAttribute((const void*)k_scan_coop, hipFuncAttributeMaxDynamicSharedMemorySize, SCAN_LDS);
  {
    void* xw_p = (void*)xw; void* whh_p = (void*)gru_Whh; void* bhh_p = (void*)gru_bhh;
    void* ha_p = (void*)h_all; void* hb0_p = (void*)hb0; void* hb1_p = (void*)hb1;
    void* args[] = {&xw_p, &whh_p, &bhh_p, &ha_p, &hb0_p, &hb1_p};
    (void)hipLaunchCooperativeKernel((const void*)k_scan_coop, dim3(SCAN_BLOCKS), dim3(SCAN_THREADS),
                                     args, SCAN_LDS, stream);
  }

  k_hwattn<<<Tt*Bb, 256, 0, stream>>>(h_all, attn_W, attn_b, hw_attn);
  k_score<<<Tt*Bb, 64, 0, stream>>>(hw_attn, enc_proj, enc, v_W, w_out, c_all);
  k_abuild<<<Tt*Bb, 256, 0, stream>>>(input_data, c_all, embedding, h_all, Abf);

  (void)hipFuncSetAttribute((const void*)k_gemm, hipFuncAttributeMaxDynamicSharedMemorySize, GEMM_LDS);
  k_gemm<<<(Vv + 63)/64, 256, GEMM_LDS, stream>>>(Abf, dense_W, dense_b, pred);

  k_lse<<<Tt*Bb, 256, 0, stream>>>(pred, lse);
  k_sub<<<Tt*Bb, 256, 0, stream>>>(pred, lse);
  k_hT<<<64, 256, 0, stream>>>(h_all, hT_out);
}

// Round 6
// 2907.419 us; speedup vs baseline: 2.7496x; 1.1165x over previous
//
#include <hip/hip_runtime.h>
#include <hip/hip_bf16.h>
#include <hip/hip_cooperative_groups.h>
#include <math.h>

namespace cg = cooperative_groups;

#define Tt 64
#define Bb 32
#define Hh 512
#define EMBe 256
#define Ee 128
#define Ss 35
#define Vv 50257
#define Kk 896
#define TCc 32

typedef __bf16 bf16_t;
typedef __bf16 bf16x4 __attribute__((ext_vector_type(4)));
typedef __bf16 bf16x8 __attribute__((ext_vector_type(8)));
typedef float f32x4 __attribute__((ext_vector_type(4)));

__device__ __forceinline__ float sigf(float x){ return 1.f/(1.f + expf(-x)); }

#define DOT4(acc, W_, H_) acc += (W_).x*(H_).x + (W_).y*(H_).y + (W_).z*(H_).z + (W_).w*(H_).w

// ---- K0a: condition embeddings -> enc rows 0..2  (enc layout [s][b][e])
__global__ void k_cond_emb(const int* __restrict__ cond, const float* __restrict__ t0,
                           const float* __restrict__ t1, const float* __restrict__ t2,
                           float* __restrict__ enc){
  int g = blockIdx.x*blockDim.x + threadIdx.x;
  if (g >= 3*Bb*Ee) return;
  int i = g/(Bb*Ee); int b = (g/Ee)%Bb; int e = g%Ee;
  const float* tbl = (i==0)? t0 : (i==1)? t1 : t2;
  int ci = cond[i*Bb + b];
  enc[(size_t)i*Bb*Ee + b*Ee + e] = tbl[(size_t)ci*Ee + e];
}

// ---- K0b: cxw[t,b,g] = cseq_emb[cond_seq[t,b]] . cgru_Wih[g] + bih[g]
__global__ void k_cxw(const int* __restrict__ cond_seq, const float* __restrict__ cemb,
                      const float* __restrict__ Wih, const float* __restrict__ bih,
                      float* __restrict__ cxw){
  __shared__ float es[Ee];
  int row = blockIdx.x; int tid = threadIdx.x; // 128 threads
  int idx = cond_seq[row];
  es[tid] = cemb[(size_t)idx*Ee + tid];
  __syncthreads();
  const float4* hp = (const float4*)es;
  for (int q = 0; q < 3; ++q){
    int g = q*Ee + tid;
    const float4* wr = (const float4*)(Wih + (size_t)g*Ee);
    float acc = bih[g];
    #pragma unroll 8
    for (int k = 0; k < Ee/4; ++k){ float4 w4 = wr[k]; float4 h4 = hp[k]; DOT4(acc, w4, h4); }
    cxw[(size_t)row*(3*Ee) + g] = acc;
  }
}

// ---- K0c: xw[t,b,g] = embedding[input[t,b]] . gru_Wih[g] + bih[g]
__global__ void k_xw(const int* __restrict__ input_data, const float* __restrict__ emb,
                     const float* __restrict__ Wih, const float* __restrict__ bih,
                     float* __restrict__ xw){
  __shared__ float es[EMBe];
  int row = blockIdx.x; int tid = threadIdx.x; // 256 threads
  int idx = input_data[row];
  es[tid] = emb[(size_t)idx*EMBe + tid];
  __syncthreads();
  const float4* hp = (const float4*)es;
  for (int q = 0; q < 6; ++q){
    int g = q*256 + tid;
    const float4* wr = (const float4*)(Wih + (size_t)g*EMBe);
    float acc = bih[g];
    #pragma unroll 8
    for (int k = 0; k < EMBe/4; ++k){ float4 w4 = wr[k]; float4 h4 = hp[k]; DOT4(acc, w4, h4); }
    xw[(size_t)row*(3*Hh) + g] = acc;
  }
}

// ---- transpose cgru_Whh [384][128] -> WT [128][384]
__global__ void k_ctrans(const float* __restrict__ W, float* __restrict__ WT){
  int idx = blockIdx.x*256 + threadIdx.x;
  if (idx >= 3*Ee*Ee) return;
  int g = idx/Ee, k = idx%Ee;
  WT[(size_t)k*(3*Ee) + g] = W[idx];
}

// ---- K1: cseq GRU scan (one block per batch), coalesced via WT, writes enc rows 3..34
__global__ void k_cseq_scan(const float* __restrict__ cxw, const float* __restrict__ WT,
                            const float* __restrict__ bhh, float* __restrict__ enc){
  __shared__ float hs[Ee];
  int b = blockIdx.x; int j = threadIdx.x; // 128 threads
  hs[j] = 0.f; __syncthreads();
  float b0 = bhh[j], b1 = bhh[Ee+j], b2 = bhh[2*Ee+j];
  for (int t = 0; t < TCc; ++t){
    const float* xp = cxw + ((size_t)t*Bb + b)*(3*Ee);
    float a0=b0, a1=b1, a2=b2;
    #pragma unroll 4
    for (int k = 0; k < Ee; ++k){
      float hk = hs[k];
      const float* wr = WT + (size_t)k*(3*Ee);
      a0 += hk * wr[j];
      a1 += hk * wr[Ee + j];
      a2 += hk * wr[2*Ee + j];
    }
    float r = sigf(xp[j] + a0);
    float z = sigf(xp[Ee + j] + a1);
    float n = tanhf(xp[2*Ee + j] + r*a2);
    float hcur = hs[j];
    float hn = (1.f - z)*n + z*hcur;
    __syncthreads();
    hs[j] = hn;
    enc[(size_t)(3+t)*Bb*Ee + b*Ee + j] = hn;
    __syncthreads();
  }
}

// ---- K2: enc_proj[b,s,h] = enc[s,b,:] . W_e[h,:]   (W_e = attn_W[:, :E])
__global__ void k_encproj(const float* __restrict__ enc, const float* __restrict__ attn_W,
                          float* __restrict__ enc_proj){
  __shared__ float es[Ee];
  int blk = blockIdx.x; int tid = threadIdx.x; // 256 threads, blk = b*35+s
  int b = blk/Ss, s = blk%Ss;
  if (tid < Ee) es[tid] = enc[(size_t)s*Bb*Ee + b*Ee + tid];
  __syncthreads();
  const float4* hp = (const float4*)es;
  for (int q = 0; q < 2; ++q){
    int hh = q*256 + tid;
    const float4* wr = (const float4*)(attn_W + (size_t)hh*(Ee+Hh));
    float acc = 0.f;
    #pragma unroll 8
    for (int k = 0; k < Ee/4; ++k){ float4 w4 = wr[k]; float4 h4 = hp[k]; DOT4(acc, w4, h4); }
    enc_proj[(size_t)blk*Hh + hh] = acc;
  }
}

// ---- K3: cooperative main GRU scan (16 blocks x 384 threads), Whh resident in LDS.
#define SCAN_BLOCKS 16
#define SCAN_THREADS 384
#define WSL_STRIDE 520
#define HST_STRIDE 520
#define GW_STRIDE 104
#define SCAN_LDS (96*WSL_STRIDE*2 + Bb*HST_STRIDE*2 + Bb*GW_STRIDE*4)

__global__ __launch_bounds__(SCAN_THREADS) void k_scan_coop(
    const float* __restrict__ xw, const float* __restrict__ Whh,
    const float* __restrict__ bhh, float* __restrict__ h_all,
    bf16_t* __restrict__ hb0, bf16_t* __restrict__ hb1){
  extern __shared__ char smem[];
  bf16_t* Wsl = (bf16_t*)smem;
  bf16_t* hst = (bf16_t*)(smem + 96*WSL_STRIDE*2);
  float*  gw  = (float*) (smem + 96*WSL_STRIDE*2 + Bb*HST_STRIDE*2);
  const int tid = threadIdx.x;
  const int blk = blockIdx.x;
  const int c0 = blk*32;

  for (int lr = 0; lr < 96; ++lr){
    int g = lr >> 5, i = lr & 31;
    const float* src = Whh + ((size_t)g*Hh + c0 + i)*Hh;
    for (int c = tid; c < Hh; c += SCAN_THREADS)
      Wsl[lr*WSL_STRIDE + c] = (bf16_t)src[c];
  }
  for (int idx = tid; idx < Bb*32; idx += SCAN_THREADS){
    int b = idx >> 5, i = idx & 31;
    hb0[b*Hh + c0 + i] = (bf16_t)0.f;
    h_all[(size_t)b*Hh + c0 + i] = 0.f;
  }

  int   ib[3], icl[3], nit = 0;
  float bhr[3], bhz[3], bhn[3], hreg[3];
  for (int i = 0; i < 3; ++i){
    int item = tid + SCAN_THREADS*i;
    if (item < Bb*32){
      ib[nit] = item >> 5; icl[nit] = item & 31;
      int j = c0 + (item & 31);
      bhr[nit] = bhh[j]; bhz[nit] = bhh[Hh + j]; bhn[nit] = bhh[2*Hh + j];
      hreg[nit] = 0.f;
      ++nit;
    }
  }

  cg::grid_group grid = cg::this_grid();
  grid.sync();

  const int wid = tid >> 6, lane = tid & 63;
  const int l15 = lane & 15, l4 = lane >> 4;

  for (int t = 0; t < Tt; ++t){
    const bf16_t* hin  = (t & 1) ? hb1 : hb0;
    bf16_t*       hout = (t & 1) ? hb0 : hb1;
    for (int idx = tid; idx < Bb*Hh/8; idx += SCAN_THREADS){
      int b = idx >> 6, c8 = idx & 63;
      *(bf16x8*)(hst + b*HST_STRIDE + c8*8) = *(const bf16x8*)(hin + b*Hh + c8*8);
    }
    __syncthreads();
    f32x4 acc0 = {0.f,0.f,0.f,0.f}, acc1 = {0.f,0.f,0.f,0.f};
    #pragma unroll
    for (int ks = 0; ks < 16; ++ks){
      bf16x8 bfr = *(const bf16x8*)(Wsl + (wid*16 + l15)*WSL_STRIDE + ks*32 + l4*8);
      bf16x8 a0  = *(const bf16x8*)(hst + l15*HST_STRIDE        + ks*32 + l4*8);
      bf16x8 a1  = *(const bf16x8*)(hst + (16 + l15)*HST_STRIDE + ks*32 + l4*8);
      acc0 = __builtin_amdgcn_mfma_f32_16x16x32_bf16(a0, bfr, acc0, 0, 0, 0);
      acc1 = __builtin_amdgcn_mfma_f32_16x16x32_bf16(a1, bfr, acc1, 0, 0, 0);
    }
    #pragma unroll
    for (int i = 0; i < 4; ++i){
      gw[(l4*4 + i)*GW_STRIDE + wid*16 + l15]        = acc0[i];
      gw[(16 + l4*4 + i)*GW_STRIDE + wid*16 + l15]   = acc1[i];
    }
    __syncthreads();
    for (int i = 0; i < nit; ++i){
      int b = ib[i], cl = icl[i], j = c0 + cl;
      const float* xp = xw + ((size_t)t*Bb + b)*(3*Hh);
      float gr = gw[b*GW_STRIDE + cl]      + bhr[i];
      float gz = gw[b*GW_STRIDE + 32 + cl] + bhz[i];
      float gn = gw[b*GW_STRIDE + 64 + cl] + bhn[i];
      float r = sigf(xp[j] + gr);
      float z = sigf(xp[Hh + j] + gz);
      float n = tanhf(xp[2*Hh + j] + r*gn);
      float hn = (1.f - z)*n + z*hreg[i];
      hreg[i] = hn;
      h_all[((size_t)(t+1)*Bb + b)*Hh + j] = hn;
      hout[b*Hh + j] = (bf16_t)hn;
    }
    grid.sync();
  }
}

// ---- K4: hw_attn[row,h] = h_all[row,:] . W_h[h,:] + attn_b[h]  (W_h = attn_W[:, E:])
__global__ void k_hwattn(const float* __restrict__ h_all, const float* __restrict__ attn_W,
                         const float* __restrict__ attn_b, float* __restrict__ hw_attn){
  __shared__ float hsr[Hh];
  int row = blockIdx.x, tid = threadIdx.x; // 256 threads
  hsr[tid]       = h_all[(size_t)row*Hh + tid];
  hsr[256 + tid] = h_all[(size_t)row*Hh + 256 + tid];
  __syncthreads();
  const float4* hp = (const float4*)hsr;
  for (int q = 0; q < 2; ++q){
    int hh = q*256 + tid;
    const float4* wr = (const float4*)(attn_W + (size_t)hh*(Ee+Hh) + Ee);
    float acc = attn_b[hh];
    #pragma unroll 4
    for (int k = 0; k < Hh/4; ++k){ float4 w4 = wr[k]; float4 h4 = hp[k]; DOT4(acc, w4, h4); }
    hw_attn[(size_t)row*Hh + hh] = acc;
  }
}

// ---- K5: score + softmax + context. One wave per (t,b) row.
__global__ void k_score(const float* __restrict__ hw_attn, const float* __restrict__ enc_proj,
                        const float* __restrict__ enc, const float* __restrict__ vW,
                        float* __restrict__ w_out, float* __restrict__ c_all){
  __shared__ float hws[Hh];
  __shared__ float sc[Ss];
  __shared__ float wsm[Ss];
  int row = blockIdx.x, lane = threadIdx.x; // 64 threads
  int b = row & (Bb-1);
  for (int k = lane; k < Hh; k += 64) hws[k] = hw_attn[(size_t)row*Hh + k];
  __syncthreads();
  for (int s = 0; s < Ss; ++s){
    const float* ep = enc_proj + ((size_t)b*Ss + s)*Hh;
    float acc = 0.f;
    for (int k = lane; k < Hh; k += 64) acc += tanhf(ep[k] + hws[k]) * vW[k];
    #pragma unroll
    for (int off = 32; off > 0; off >>= 1) acc += __shfl_xor(acc, off);
    if (lane == 0) sc[s] = acc;
  }
  __syncthreads();
  float val = (lane < Ss) ? sc[lane] : -3.0e38f;
  float mx = val;
  #pragma unroll
  for (int off = 32; off > 0; off >>= 1) mx = fmaxf(mx, __shfl_xor(mx, off));
  float e = (lane < Ss) ? expf(val - mx) : 0.f;
  float sm = e;
  #pragma unroll
  for (int off = 32; off > 0; off >>= 1) sm += __shfl_xor(sm, off);
  float w = e / sm;
  if (lane < Ss){ w_out[(size_t)row*Ss + lane] = w; wsm[lane] = w; }
  __syncthreads();
  for (int q = 0; q < 2; ++q){
    int ee = q*64 + lane;
    float acc = 0.f;
    #pragma unroll
    for (int s = 0; s < Ss; ++s) acc += wsm[s]*enc[(size_t)s*Bb*Ee + b*Ee + ee];
    c_all[(size_t)row*Ee + ee] = acc;
  }
}

// ---- K6: build A = [c | x_emb | h] as bf16, row-major [2048][896]
__global__ void k_abuild(const int* __restrict__ input_data, const float* __restrict__ c_all,
                         const float* __restrict__ embedding, const float* __restrict__ h_all,
                         bf16_t* __restrict__ A){
  int row = blockIdx.x, tid = threadIdx.x; // 256 threads
  int xidx = input_data[row];
  bf16_t* Ar = A + (size_t)row*Kk;
  for (int col = tid; col < Kk; col += 256){
    float v;
    if (col < Ee) v = c_all[(size_t)row*Ee + col];
    else if (col < Ee + EMBe) v = embedding[(size_t)xidx*EMBe + (col - Ee)];
    else v = h_all[(size_t)row*Hh + (col - Ee - EMBe)];
    Ar[col] = (bf16_t)v;
  }
}

// ---- K7: dense GEMM, 128x128x64 double-buffered tiles.
// grid (16 mt x 393 nt), mt fastest -> 16 consecutive blocks share one W panel (L2/L3 reuse).
#define BM 128
#define BN 128
#define BK 64
#define NKK (Kk/BK)
#define GST 72
#define GEMM_LDS (2*(BM*GST + BN*GST)*2)

__global__ __launch_bounds__(256) void k_gemm(const bf16_t* __restrict__ A,
                                              const float* __restrict__ Wd,
                                              const float* __restrict__ bias,
                                              float* __restrict__ out){
  extern __shared__ char smem[];
  bf16_t* As = (bf16_t*)smem;                          // [2][BM][GST]
  bf16_t* Ws = (bf16_t*)(smem + 2*BM*GST*2);           // [2][BN][GST]
  const int tid = threadIdx.x;
  const int m0 = blockIdx.x*BM, n0 = blockIdx.y*BN;
  const int arow = tid >> 1, acl = (tid & 1)*32;       // A: 2 thr/row, 32 bf16 each
  const int wrow = tid >> 4, wc = (tid & 15)*4;        // W: 16 thr/row, 4 fp32 each, 8 row-groups

  int4 aR0, aR1, aR2, aR3;
  float4 wR[8];

#define LOAD_TILE(KK) { \
    const int4* ap = (const int4*)(A + (size_t)(m0 + arow)*Kk + (KK)*BK + acl); \
    aR0 = ap[0]; aR1 = ap[1]; aR2 = ap[2]; aR3 = ap[3]; \
    _Pragma("unroll") \
    for (int r = 0; r < 8; ++r){ \
      int vrow = n0 + wrow + r*16; \
      if (vrow < Vv) wR[r] = *(const float4*)(Wd + (size_t)vrow*Kk + (KK)*BK + wc); \
      else wR[r] = make_float4(0.f,0.f,0.f,0.f); \
    } }

#define WRITE_TILE(BUF) { \
    int4* ad = (int4*)(As + (BUF)*BM*GST + arow*GST + acl); \
    ad[0]=aR0; ad[1]=aR1; ad[2]=aR2; ad[3]=aR3; \
    _Pragma("unroll") \
    for (int r = 0; r < 8; ++r){ \
      bf16x4 p; p[0]=(bf16_t)wR[r].x; p[1]=(bf16_t)wR[r].y; p[2]=(bf16_t)wR[r].z; p[3]=(bf16_t)wR[r].w; \
      *(bf16x4*)(Ws + (BUF)*BN*GST + (wrow + r*16)*GST + wc) = p; \
    } }

  const int wave = tid >> 6, lane = tid & 63;
  const int l15 = lane & 15, l4 = lane >> 4;

  f32x4 acc[2][8];
  #pragma unroll
  for (int i = 0; i < 2; ++i)
    #pragma unroll
    for (int j = 0; j < 8; ++j) acc[i][j] = (f32x4){0.f,0.f,0.f,0.f};

  LOAD_TILE(0);
  WRITE_TILE(0);
  int cur = 0;
  for (int kk = 0; kk < NKK; ++kk){
    __syncthreads();
    if (kk + 1 < NKK) LOAD_TILE(kk + 1);
    const bf16_t* Ab = As + cur*BM*GST;
    const bf16_t* Wb = Ws + cur*BN*GST;
    #pragma unroll
    for (int k32 = 0; k32 < 2; ++k32){
      bf16x8 a0 = *(const bf16x8*)(Ab + (wave*32 +      l15)*GST + k32*32 + l4*8);
      bf16x8 a1 = *(const bf16x8*)(Ab + (wave*32 + 16 + l15)*GST + k32*32 + l4*8);
      #pragma unroll
      for (int nf = 0; nf < 8; ++nf){
        bf16x8 bfr = *(const bf16x8*)(Wb + (nf*16 + l15)*GST + k32*32 + l4*8);
        acc[0][nf] = __builtin_amdgcn_mfma_f32_16x16x32_bf16(a0, bfr, acc[0][nf], 0, 0, 0);
        acc[1][nf] = __builtin_amdgcn_mfma_f32_16x16x32_bf16(a1, bfr, acc[1][nf], 0, 0, 0);
      }
    }
    __syncthreads();
    if (kk + 1 < NKK){ WRITE_TILE(cur ^ 1); cur ^= 1; }
  }
  // epilogue: D row(M) = (l>>4)*4 + reg, col(N) = l&15
  #pragma unroll
  for (int mf = 0; mf < 2; ++mf){
    #pragma unroll
    for (int nf = 0; nf < 8; ++nf){
      int v = n0 + nf*16 + l15;
      if (v < Vv){
        float bv = bias[v];
        int m = m0 + wave*32 + mf*16 + l4*4;
        #pragma unroll
        for (int i = 0; i < 4; ++i){
          out[(size_t)(m + i)*Vv + v] = acc[mf][nf][i] + bv;
        }
      }
    }
  }
#undef LOAD_TILE
#undef WRITE_TILE
}

// ---- K8: per-row online logsumexp
__global__ void k_lse(const float* __restrict__ pred, float* __restrict__ lse){
  __shared__ float ms[256], ssum[256];
  int row = blockIdx.x, tid = threadIdx.x;
  const float* p = pred + (size_t)row*Vv;
  float m = -3.0e38f, s = 0.f;
  for (int v = tid; v < Vv; v += 256){
    float x = p[v];
    if (x > m){ s = s*expf(m - x) + 1.f; m = x; }
    else s += expf(x - m);
  }
  ms[tid] = m; ssum[tid] = s;
  __syncthreads();
  for (int off = 128; off > 0; off >>= 1){
    if (tid < off){
      float m2 = ms[tid+off], s2 = ssum[tid+off];
      float m1 = ms[tid],     s1 = ssum[tid];
      if (m2 > m1){ s1 = s1*expf(m1 - m2) + s2; m1 = m2; }
      else s1 += s2*expf(m2 - m1);
      ms[tid] = m1; ssum[tid] = s1;
    }
    __syncthreads();
  }
  if (tid == 0) lse[row] = ms[0] + logf(ssum[0]);
}

// ---- K9: pred -= lse[row]
__global__ void k_sub(float* __restrict__ pred, const float* __restrict__ lse){
  int row = blockIdx.x, tid = threadIdx.x;
  float l = lse[row];
  float* p = pred + (size_t)row*Vv;
  for (int v = tid; v < Vv; v += 256) p[v] -= l;
}

// ---- K10: copy hT
__global__ void k_hT(const float* __restrict__ h_all, float* __restrict__ hT){
  int g = blockIdx.x*256 + threadIdx.x;
  if (g < Bb*Hh) hT[g] = h_all[(size_t)Tt*Bb*Hh + g];
}

extern "C" void kernel_launch(void* const* d_in, const int* in_sizes, int n_in,
                              void* d_out, int out_size, void* d_ws, size_t ws_size,
                              hipStream_t stream){
  const int*   input_data = (const int*)d_in[0];
  const int*   condition  = (const int*)d_in[1];
  const int*   cond_seq   = (const int*)d_in[2];
  const float* emb_c0     = (const float*)d_in[3];
  const float* emb_c1     = (const float*)d_in[4];
  const float* emb_c2     = (const float*)d_in[5];
  const float* cseq_emb   = (const float*)d_in[6];
  const float* embedding  = (const float*)d_in[7];
  const float* attn_W     = (const float*)d_in[8];
  const float* attn_b     = (const float*)d_in[9];
  const float* v_W        = (const float*)d_in[10];
  const float* gru_Wih    = (const float*)d_in[11];
  const float* gru_Whh    = (const float*)d_in[12];
  const float* gru_bih    = (const float*)d_in[13];
  const float* gru_bhh    = (const float*)d_in[14];
  const float* cgru_Wih   = (const float*)d_in[15];
  const float* cgru_Whh   = (const float*)d_in[16];
  const float* cgru_bih   = (const float*)d_in[17];
  const float* cgru_bhh   = (const float*)d_in[18];
  const float* dense_W    = (const float*)d_in[19];
  const float* dense_b    = (const float*)d_in[20];

  float* out    = (float*)d_out;
  float* pred   = out;                              // [2048][V]
  float* hT_out = out + (size_t)Tt*Bb*Vv;           // [32][512]
  float* w_out  = hT_out + (size_t)Bb*Hh;           // [2048][35]

  float* ws       = (float*)d_ws;
  float* h_all    = ws;                                   // 65*32*512
  float* xw       = h_all + (size_t)(Tt+1)*Bb*Hh;         // 64*32*1536
  float* cxw      = xw + (size_t)Tt*Bb*3*Hh;              // 32*32*384
  float* enc      = cxw + (size_t)TCc*Bb*3*Ee;            // 35*32*128
  float* enc_proj = enc + (size_t)Ss*Bb*Ee;               // 32*35*512
  float* hw_attn  = enc_proj + (size_t)Bb*Ss*Hh;          // 64*32*512
  float* c_all    = hw_attn + (size_t)Tt*Bb*Hh;           // 64*32*128
  float* lse      = c_all + (size_t)Tt*Bb*Ee;             // 2048
  bf16_t* Abf     = (bf16_t*)(lse + Tt*Bb);               // 2048*896 bf16
  float* after_A  = (float*)(Abf + (size_t)Tt*Bb*Kk);
  bf16_t* hb0     = (bf16_t*)after_A;                     // 32*512 bf16
  bf16_t* hb1     = hb0 + (size_t)Bb*Hh;                  // 32*512 bf16
  float* WTc      = (float*)(hb1 + (size_t)Bb*Hh);        // 128*384 fp32

  k_cond_emb<<<48, 256, 0, stream>>>(condition, emb_c0, emb_c1, emb_c2, enc);
  k_cxw<<<TCc*Bb, 128, 0, stream>>>(cond_seq, cseq_emb, cgru_Wih, cgru_bih, cxw);
  k_xw<<<Tt*Bb, 256, 0, stream>>>(input_data, embedding, gru_Wih, gru_bih, xw);
  k_ctrans<<<(3*Ee*Ee + 255)/256, 256, 0, stream>>>(cgru_Whh, WTc);
  k_cseq_scan<<<Bb, Ee, 0, stream>>>(cxw, WTc, cgru_bhh, enc);
  k_encproj<<<Bb*Ss, 256, 0, stream>>>(enc, attn_W, enc_proj);

  (void)hipFuncSetAttribute((const void*)k_scan_coop, hipFuncAttributeMaxDynamicSharedMemorySize, SCAN_LDS);
  {
    void* xw_p = (void*)xw; void* whh_p = (void*)gru_Whh; void* bhh_p = (void*)gru_bhh;
    void* ha_p = (void*)h_all; void* hb0_p = (void*)hb0; void* hb1_p = (void*)hb1;
    void* args[] = {&xw_p, &whh_p, &bhh_p, &ha_p, &hb0_p, &hb1_p};
    (void)hipLaunchCooperativeKernel((const void*)k_scan_coop, dim3(SCAN_BLOCKS), dim3(SCAN_THREADS),
                                     args, SCAN_LDS, stream);
  }

  k_hwattn<<<Tt*Bb, 256, 0, stream>>>(h_all, attn_W, attn_b, hw_attn);
  k_score<<<Tt*Bb, 64, 0, stream>>>(hw_attn, enc_proj, enc, v_W, w_out, c_all);
  k_abuild<<<Tt*Bb, 256, 0, stream>>>(input_data, c_all, embedding, h_all, Abf);

  (void)hipFuncSetAttribute((const void*)k_gemm, hipFuncAttributeMaxDynamicSharedMemorySize, GEMM_LDS);
  k_gemm<<<dim3(16, (Vv + BN - 1)/BN), 256, GEMM_LDS, stream>>>(Abf, dense_W, dense_b, pred);

  k_lse<<<Tt*Bb, 256, 0, stream>>>(pred, lse);
  k_sub<<<Tt*Bb, 256, 0, stream>>>(pred, lse);
  k_hT<<<64, 256, 0, stream>>>(h_all, hT_out);
}